// Round 1
// baseline (2512.475 us; speedup 1.0000x reference)
//
#include <hip/hip_runtime.h>
#include <hip/hip_bf16.h>

#define N_NODES 200000
#define N_EDGES 800000
#define N_MOL   10000
#define HDIM    64
#define EDGE_DIM 16
#define BN_EPS 1e-5f

// ---------------------------------------------------------------------------
// Edge kernel: msg = relu(x[src] + edge_attr @ We.T + be); atomicAdd into agg[dst]
// One 64-lane wave per edge (4 edges per 256-thread block).
// ---------------------------------------------------------------------------
template<int DIN>
__global__ __launch_bounds__(256) void edge_kernel(
    const float* __restrict__ xin, int stride_in,
    const int*   __restrict__ ei,     // [2, E]
    const float* __restrict__ ea,     // [E, 16]
    const float* __restrict__ We,     // [DIN, 16]
    const float* __restrict__ be,     // [DIN]
    float*       __restrict__ agg)    // [N, 64] (zeroed)
{
    int lane = threadIdx.x & 63;
    int e = blockIdx.x * 4 + (threadIdx.x >> 6);
    if (e >= N_EDGES) return;
    int src = ei[e];
    int dst = ei[N_EDGES + e];
    float eav = (lane < EDGE_DIM) ? ea[e * EDGE_DIM + lane] : 0.f;

    // broadcast the 16 edge-attr values to all lanes
    float ej[16];
#pragma unroll
    for (int j = 0; j < 16; j++) ej[j] = __shfl(eav, j, 64);

    int f = lane;
    if (f < DIN) {
        const float4* w4 = reinterpret_cast<const float4*>(We + f * 16);
        float acc = be[f];
#pragma unroll
        for (int j = 0; j < 4; j++) {
            float4 w = w4[j];
            acc += w.x * ej[4 * j + 0] + w.y * ej[4 * j + 1]
                 + w.z * ej[4 * j + 2] + w.w * ej[4 * j + 3];
        }
        float msg = xin[(size_t)src * stride_in + f] + acc;
        msg = fmaxf(msg, 0.f);
        atomicAdd(&agg[(size_t)dst * HDIM + f], msg);
    }
}

// ---------------------------------------------------------------------------
// Node kernel: h = leaky_relu(BN((x + agg) @ W.T + b)) ; written in place into B
// One 64-lane wave per node (4 nodes per block). Lane = output feature.
// ---------------------------------------------------------------------------
template<int DIN>
__global__ __launch_bounds__(256) void node_kernel(
    const float* __restrict__ xin, int stride_in,
    float*       __restrict__ B,      // agg in (cols 0..DIN-1) / h out [N,64]
    const float* __restrict__ W,      // [64, DIN]
    const float* __restrict__ b,
    const float* __restrict__ g,
    const float* __restrict__ bb,
    const float* __restrict__ m,
    const float* __restrict__ v)
{
    int lane = threadIdx.x & 63;
    int i = blockIdx.x * 4 + (threadIdx.x >> 6);
    if (i >= N_NODES) return;

    float sval = 0.f;
    if (lane < DIN) sval = xin[(size_t)i * stride_in + lane] + B[(size_t)i * HDIM + lane];

    const float4* w4 = reinterpret_cast<const float4*>(W + lane * DIN);
    float acc = b[lane];
#pragma unroll
    for (int j = 0; j < DIN / 4; j++) {
        float4 w = w4[j];
        acc += w.x * __shfl(sval, 4 * j + 0, 64)
             + w.y * __shfl(sval, 4 * j + 1, 64)
             + w.z * __shfl(sval, 4 * j + 2, 64)
             + w.w * __shfl(sval, 4 * j + 3, 64);
    }
    float scale = g[lane] * rsqrtf(v[lane] + BN_EPS);
    float y = scale * (acc - m[lane]) + bb[lane];
    B[(size_t)i * HDIM + lane] = (y > 0.f) ? y : 0.01f * y;
}

// ---------------------------------------------------------------------------
// Pool kernel: hpool[batch[i]] += h3[i]  (atomics; batch sorted, ~20 nodes/mol)
// ---------------------------------------------------------------------------
__global__ __launch_bounds__(256) void pool_kernel(
    const float* __restrict__ h3,
    const int*   __restrict__ batch,
    float*       __restrict__ hpool)
{
    int gid = blockIdx.x * 256 + threadIdx.x;
    if (gid >= N_NODES * HDIM) return;
    int i = gid >> 6, f = gid & 63;
    atomicAdd(&hpool[(size_t)batch[i] * HDIM + f], h3[gid]);
}

// ---------------------------------------------------------------------------
// Final fused MLP head:
//   z = concat(h1,h2,h3,hpool[batch])  [256]
//   a = leaky_relu(Wl1 @ z + bl1)      [256]
//   out = Wl2 . a + bl2                scalar
// Block = 256 threads, 32 nodes staged in LDS; thread t owns out-feature t.
// ---------------------------------------------------------------------------
__global__ __launch_bounds__(256) void final_kernel(
    const float* __restrict__ h1, const float* __restrict__ h2,
    const float* __restrict__ h3, const float* __restrict__ hpool,
    const int*   __restrict__ batch,
    const float* __restrict__ Wl1, const float* __restrict__ bl1,
    const float* __restrict__ Wl2, const float* __restrict__ bl2,
    float*       __restrict__ out)
{
    __shared__ float zs[32][256];
    __shared__ float wavered[32][4];
    int tid = threadIdx.x;
    int n0 = blockIdx.x * 32;

    // stage z for 32 nodes
#pragma unroll
    for (int n = 0; n < 32; n++) {
        int c = tid;
        int i = n0 + n;
        float val;
        if (c < 64)       val = h1[(size_t)i * 64 + c];
        else if (c < 128) val = h2[(size_t)i * 64 + (c - 64)];
        else if (c < 192) val = h3[(size_t)i * 64 + (c - 128)];
        else              val = hpool[(size_t)batch[i] * 64 + (c - 192)];
        zs[n][c] = val;
    }
    __syncthreads();

    int f = tid;
    float acc[32];
    float bias = bl1[f];
#pragma unroll
    for (int n = 0; n < 32; n++) acc[n] = bias;

    const float4* wrow = reinterpret_cast<const float4*>(Wl1 + (size_t)f * 256);
#pragma unroll 1
    for (int kc = 0; kc < 4; kc++) {
        float4 w[16];
#pragma unroll
        for (int j = 0; j < 16; j++) w[j] = wrow[kc * 16 + j];
#pragma unroll
        for (int n = 0; n < 32; n++) {
            const float4* z4 = reinterpret_cast<const float4*>(&zs[n][kc * 64]);
            float s = 0.f;
#pragma unroll
            for (int j = 0; j < 16; j++) {
                float4 zz = z4[j];
                s += w[j].x * zz.x + w[j].y * zz.y + w[j].z * zz.z + w[j].w * zz.w;
            }
            acc[n] += s;
        }
    }

    float wl2 = Wl2[f];
    int lane = tid & 63, wv = tid >> 6;
#pragma unroll
    for (int n = 0; n < 32; n++) {
        float a = acc[n];
        a = (a > 0.f) ? a : 0.01f * a;
        float p = wl2 * a;
#pragma unroll
        for (int off = 32; off > 0; off >>= 1) p += __shfl_down(p, off, 64);
        if (lane == 0) wavered[n][wv] = p;
    }
    __syncthreads();
    if (tid < 32) {
        out[n0 + tid] = bl2[0] + wavered[tid][0] + wavered[tid][1]
                      + wavered[tid][2] + wavered[tid][3];
    }
}

// ---------------------------------------------------------------------------
extern "C" void kernel_launch(void* const* d_in, const int* in_sizes, int n_in,
                              void* d_out, int out_size, void* d_ws, size_t ws_size,
                              hipStream_t stream) {
    const float* x     = (const float*)d_in[0];
    const int*   ei    = (const int*)  d_in[1];
    const float* ea    = (const float*)d_in[2];
    const int*   batch = (const int*)  d_in[3];

    const float* We1 = (const float*)d_in[4];  const float* be1 = (const float*)d_in[5];
    const float* W1  = (const float*)d_in[6];  const float* b1  = (const float*)d_in[7];
    const float* g1  = (const float*)d_in[8];  const float* bb1 = (const float*)d_in[9];
    const float* m1  = (const float*)d_in[10]; const float* v1  = (const float*)d_in[11];

    const float* We2 = (const float*)d_in[12]; const float* be2 = (const float*)d_in[13];
    const float* W2  = (const float*)d_in[14]; const float* b2  = (const float*)d_in[15];
    const float* g2  = (const float*)d_in[16]; const float* bb2 = (const float*)d_in[17];
    const float* m2  = (const float*)d_in[18]; const float* v2  = (const float*)d_in[19];

    const float* We3 = (const float*)d_in[20]; const float* be3 = (const float*)d_in[21];
    const float* W3  = (const float*)d_in[22]; const float* b3  = (const float*)d_in[23];
    const float* g3  = (const float*)d_in[24]; const float* bb3 = (const float*)d_in[25];
    const float* m3  = (const float*)d_in[26]; const float* v3  = (const float*)d_in[27];

    const float* Wl1 = (const float*)d_in[28]; const float* bl1 = (const float*)d_in[29];
    const float* Wl2 = (const float*)d_in[30]; const float* bl2 = (const float*)d_in[31];

    float* out = (float*)d_out;

    float* B1    = (float*)d_ws;                 // [N,64] agg1 -> h1
    float* B2    = B1 + (size_t)N_NODES * HDIM;  // [N,64] agg2 -> h2
    float* B3    = B2 + (size_t)N_NODES * HDIM;  // [N,64] agg3 -> h3
    float* hpool = B3 + (size_t)N_NODES * HDIM;  // [N_MOL,64]

    size_t zero_bytes = ((size_t)3 * N_NODES * HDIM + (size_t)N_MOL * HDIM) * sizeof(float);
    hipMemsetAsync(B1, 0, zero_bytes, stream);

    dim3 blk(256);
    dim3 egrid(N_EDGES / 4);
    dim3 ngrid(N_NODES / 4);
    dim3 pgrid((N_NODES * HDIM) / 256);
    dim3 fgrid(N_NODES / 32);

    // layer 1
    edge_kernel<40><<<egrid, blk, 0, stream>>>(x, 40, ei, ea, We1, be1, B1);
    node_kernel<40><<<ngrid, blk, 0, stream>>>(x, 40, B1, W1, b1, g1, bb1, m1, v1);
    // layer 2
    edge_kernel<64><<<egrid, blk, 0, stream>>>(B1, 64, ei, ea, We2, be2, B2);
    node_kernel<64><<<ngrid, blk, 0, stream>>>(B1, 64, B2, W2, b2, g2, bb2, m2, v2);
    // layer 3
    edge_kernel<64><<<egrid, blk, 0, stream>>>(B2, 64, ei, ea, We3, be3, B3);
    node_kernel<64><<<ngrid, blk, 0, stream>>>(B2, 64, B3, W3, b3, g3, bb3, m3, v3);
    // pool
    pool_kernel<<<pgrid, blk, 0, stream>>>(B3, batch, hpool);
    // head
    final_kernel<<<fgrid, blk, 0, stream>>>(B1, B2, B3, hpool, batch,
                                            Wl1, bl1, Wl2, bl2, out);
}

// Round 2
// 1636.545 us; speedup vs baseline: 1.5352x; 1.5352x over previous
//
#include <hip/hip_runtime.h>
#include <hip/hip_bf16.h>

#define N_NODES 200000
#define N_EDGES 800000
#define N_MOL   10000
#define HDIM    64
#define EDGE_DIM 16
#define BN_EPS 1e-5f

typedef __attribute__((ext_vector_type(8))) short short8;
typedef __attribute__((ext_vector_type(4))) float f32x4;

// ---------------------------------------------------------------------------
// Edge kernel: msg = relu(x[src] + edge_attr @ We.T + be); atomicAdd into agg[dst]
// One 64-lane wave per edge (4 edges per 256-thread block).
// ---------------------------------------------------------------------------
template<int DIN>
__global__ __launch_bounds__(256) void edge_kernel(
    const float* __restrict__ xin, int stride_in,
    const int*   __restrict__ ei,     // [2, E]
    const float* __restrict__ ea,     // [E, 16]
    const float* __restrict__ We,     // [DIN, 16]
    const float* __restrict__ be,     // [DIN]
    float*       __restrict__ agg)    // [N, 64] (zeroed)
{
    int lane = threadIdx.x & 63;
    int e = blockIdx.x * 4 + (threadIdx.x >> 6);
    if (e >= N_EDGES) return;
    int src = ei[e];
    int dst = ei[N_EDGES + e];
    float eav = (lane < EDGE_DIM) ? ea[e * EDGE_DIM + lane] : 0.f;

    float ej[16];
#pragma unroll
    for (int j = 0; j < 16; j++) ej[j] = __shfl(eav, j, 64);

    int f = lane;
    if (f < DIN) {
        const float4* w4 = reinterpret_cast<const float4*>(We + f * 16);
        float acc = be[f];
#pragma unroll
        for (int j = 0; j < 4; j++) {
            float4 w = w4[j];
            acc += w.x * ej[4 * j + 0] + w.y * ej[4 * j + 1]
                 + w.z * ej[4 * j + 2] + w.w * ej[4 * j + 3];
        }
        float msg = xin[(size_t)src * stride_in + f] + acc;
        msg = fmaxf(msg, 0.f);
        atomicAdd(&agg[(size_t)dst * HDIM + f], msg);
    }
}

// ---------------------------------------------------------------------------
// Node kernel: h = leaky_relu(BN((x + agg) @ W.T + b)) ; written in place into B
// ---------------------------------------------------------------------------
template<int DIN>
__global__ __launch_bounds__(256) void node_kernel(
    const float* __restrict__ xin, int stride_in,
    float*       __restrict__ B,      // agg in / h out [N,64]
    const float* __restrict__ W,      // [64, DIN]
    const float* __restrict__ b,
    const float* __restrict__ g,
    const float* __restrict__ bb,
    const float* __restrict__ m,
    const float* __restrict__ v)
{
    int lane = threadIdx.x & 63;
    int i = blockIdx.x * 4 + (threadIdx.x >> 6);
    if (i >= N_NODES) return;

    float sval = 0.f;
    if (lane < DIN) sval = xin[(size_t)i * stride_in + lane] + B[(size_t)i * HDIM + lane];

    const float4* w4 = reinterpret_cast<const float4*>(W + lane * DIN);
    float acc = b[lane];
#pragma unroll
    for (int j = 0; j < DIN / 4; j++) {
        float4 w = w4[j];
        acc += w.x * __shfl(sval, 4 * j + 0, 64)
             + w.y * __shfl(sval, 4 * j + 1, 64)
             + w.z * __shfl(sval, 4 * j + 2, 64)
             + w.w * __shfl(sval, 4 * j + 3, 64);
    }
    float scale = g[lane] * rsqrtf(v[lane] + BN_EPS);
    float y = scale * (acc - m[lane]) + bb[lane];
    B[(size_t)i * HDIM + lane] = (y > 0.f) ? y : 0.01f * y;
}

// ---------------------------------------------------------------------------
// Pool kernel: hpool[batch[i]] += h3[i]
// ---------------------------------------------------------------------------
__global__ __launch_bounds__(256) void pool_kernel(
    const float* __restrict__ h3,
    const int*   __restrict__ batch,
    float*       __restrict__ hpool)
{
    int gid = blockIdx.x * 256 + threadIdx.x;
    if (gid >= N_NODES * HDIM) return;
    int i = gid >> 6, f = gid & 63;
    atomicAdd(&hpool[(size_t)batch[i] * HDIM + f], h3[gid]);
}

// ---------------------------------------------------------------------------
// bf16 helpers
// ---------------------------------------------------------------------------
__device__ __forceinline__ unsigned int pk2(float a, float b) {
    __hip_bfloat162 h = __float22bfloat162_rn(make_float2(a, b));
    union { __hip_bfloat162 h; unsigned int u; } c;
    c.h = h;
    return c.u;
}
__device__ __forceinline__ short8 cvt8(float4 a, float4 b) {
    union { short8 s; unsigned int u[4]; } r;
    r.u[0] = pk2(a.x, a.y); r.u[1] = pk2(a.z, a.w);
    r.u[2] = pk2(b.x, b.y); r.u[3] = pk2(b.z, b.w);
    return r.s;
}

// ---------------------------------------------------------------------------
// Head: out[i] = Wl2 . leaky(Wl1 @ z_i + bl1) + bl2,  z_i = [h1|h2|h3|hpool[batch]]
// MFMA 16x16x32 bf16, fp32 accum. One wave per 64 nodes (4 subtiles of 16).
// A = Wl1 (row=feat, k), B = z rows (col=node, k). D: col=node(lane&15),
// row=feat subrow (lane>>4)*4+reg. Second GEMM (Wl2) fused as per-lane
// reduction + shfl_xor across the 4 lane-groups.
// ---------------------------------------------------------------------------
__global__ __launch_bounds__(256) void head_kernel(
    const float* __restrict__ h1, const float* __restrict__ h2,
    const float* __restrict__ h3, const float* __restrict__ hpool,
    const int*   __restrict__ batch,
    const float* __restrict__ Wl1, const float* __restrict__ bl1,
    const float* __restrict__ Wl2, const float* __restrict__ bl2,
    float*       __restrict__ out)
{
    int lane = threadIdx.x & 63;
    int wave = blockIdx.x * 4 + (threadIdx.x >> 6);
    if (wave >= N_NODES / 64) return;
    int n0 = wave * 64;
    int r = lane & 15;       // node within subtile (B col) / A row
    int g = lane >> 4;       // k-group

    // ---- load B fragments (z rows) once: 4 node-subtiles x 8 k-steps ----
    short8 zf[4][8];
#pragma unroll
    for (int nt = 0; nt < 4; nt++) {
        int node = n0 + nt * 16 + r;
        const float* r1 = h1 + (size_t)node * 64;
        const float* r2 = h2 + (size_t)node * 64;
        const float* r3 = h3 + (size_t)node * 64;
        const float* rp = hpool + (size_t)batch[node] * 64;
        const float4* q;
        q = (const float4*)(r1 + g * 8);        zf[nt][0] = cvt8(q[0], q[1]);
        q = (const float4*)(r1 + 32 + g * 8);   zf[nt][1] = cvt8(q[0], q[1]);
        q = (const float4*)(r2 + g * 8);        zf[nt][2] = cvt8(q[0], q[1]);
        q = (const float4*)(r2 + 32 + g * 8);   zf[nt][3] = cvt8(q[0], q[1]);
        q = (const float4*)(r3 + g * 8);        zf[nt][4] = cvt8(q[0], q[1]);
        q = (const float4*)(r3 + 32 + g * 8);   zf[nt][5] = cvt8(q[0], q[1]);
        q = (const float4*)(rp + g * 8);        zf[nt][6] = cvt8(q[0], q[1]);
        q = (const float4*)(rp + 32 + g * 8);   zf[nt][7] = cvt8(q[0], q[1]);
    }

    float p[4] = {0.f, 0.f, 0.f, 0.f};

    const float4* bl1_4 = (const float4*)bl1;
    const float4* wl2_4 = (const float4*)Wl2;

#pragma unroll 1
    for (int ft = 0; ft < 16; ft++) {
        // A fragments: Wl1 rows feat = ft*16 + r, k = ks*32 + g*8 .. +8
        const float* arow = Wl1 + (size_t)(ft * 16 + r) * 256 + g * 8;
        short8 af[8];
#pragma unroll
        for (int ks = 0; ks < 8; ks++) {
            const float4* q = (const float4*)(arow + ks * 32);
            af[ks] = cvt8(q[0], q[1]);
        }

        f32x4 acc[4];
#pragma unroll
        for (int nt = 0; nt < 4; nt++) acc[nt] = (f32x4){0.f, 0.f, 0.f, 0.f};

#pragma unroll
        for (int ks = 0; ks < 8; ks++) {
#pragma unroll
            for (int nt = 0; nt < 4; nt++) {
                acc[nt] = __builtin_amdgcn_mfma_f32_16x16x32_bf16(
                    af[ks], zf[nt][ks], acc[nt], 0, 0, 0);
            }
        }

        // fuse bias + leaky + Wl2 dot. rows owned by this lane: ft*16+g*4+{0..3}
        float4 bl = bl1_4[ft * 4 + g];
        float4 w2 = wl2_4[ft * 4 + g];
#pragma unroll
        for (int nt = 0; nt < 4; nt++) {
            float a0 = acc[nt][0] + bl.x;
            float a1 = acc[nt][1] + bl.y;
            float a2 = acc[nt][2] + bl.z;
            float a3 = acc[nt][3] + bl.w;
            a0 = (a0 > 0.f) ? a0 : 0.01f * a0;
            a1 = (a1 > 0.f) ? a1 : 0.01f * a1;
            a2 = (a2 > 0.f) ? a2 : 0.01f * a2;
            a3 = (a3 > 0.f) ? a3 : 0.01f * a3;
            p[nt] += w2.x * a0 + w2.y * a1 + w2.z * a2 + w2.w * a3;
        }
    }

    // reduce across the 4 k-groups (lanes differing in bits 4,5)
    float b2 = bl2[0];
#pragma unroll
    for (int nt = 0; nt < 4; nt++) {
        float s = p[nt];
        s += __shfl_xor(s, 16, 64);
        s += __shfl_xor(s, 32, 64);
        if (g == 0) out[n0 + nt * 16 + r] = s + b2;
    }
}

// ---------------------------------------------------------------------------
extern "C" void kernel_launch(void* const* d_in, const int* in_sizes, int n_in,
                              void* d_out, int out_size, void* d_ws, size_t ws_size,
                              hipStream_t stream) {
    const float* x     = (const float*)d_in[0];
    const int*   ei    = (const int*)  d_in[1];
    const float* ea    = (const float*)d_in[2];
    const int*   batch = (const int*)  d_in[3];

    const float* We1 = (const float*)d_in[4];  const float* be1 = (const float*)d_in[5];
    const float* W1  = (const float*)d_in[6];  const float* b1  = (const float*)d_in[7];
    const float* g1  = (const float*)d_in[8];  const float* bb1 = (const float*)d_in[9];
    const float* m1  = (const float*)d_in[10]; const float* v1  = (const float*)d_in[11];

    const float* We2 = (const float*)d_in[12]; const float* be2 = (const float*)d_in[13];
    const float* W2  = (const float*)d_in[14]; const float* b2  = (const float*)d_in[15];
    const float* g2  = (const float*)d_in[16]; const float* bb2 = (const float*)d_in[17];
    const float* m2  = (const float*)d_in[18]; const float* v2  = (const float*)d_in[19];

    const float* We3 = (const float*)d_in[20]; const float* be3 = (const float*)d_in[21];
    const float* W3  = (const float*)d_in[22]; const float* b3  = (const float*)d_in[23];
    const float* g3  = (const float*)d_in[24]; const float* bb3 = (const float*)d_in[25];
    const float* m3  = (const float*)d_in[26]; const float* v3  = (const float*)d_in[27];

    const float* Wl1 = (const float*)d_in[28]; const float* bl1 = (const float*)d_in[29];
    const float* Wl2 = (const float*)d_in[30]; const float* bl2 = (const float*)d_in[31];

    float* out = (float*)d_out;

    float* B1    = (float*)d_ws;                 // [N,64] agg1 -> h1
    float* B2    = B1 + (size_t)N_NODES * HDIM;  // [N,64] agg2 -> h2
    float* B3    = B2 + (size_t)N_NODES * HDIM;  // [N,64] agg3 -> h3
    float* hpool = B3 + (size_t)N_NODES * HDIM;  // [N_MOL,64]

    size_t zero_bytes = ((size_t)3 * N_NODES * HDIM + (size_t)N_MOL * HDIM) * sizeof(float);
    hipMemsetAsync(B1, 0, zero_bytes, stream);

    dim3 blk(256);
    dim3 egrid(N_EDGES / 4);
    dim3 ngrid(N_NODES / 4);
    dim3 pgrid((N_NODES * HDIM) / 256);
    dim3 hgrid((N_NODES / 64 + 3) / 4);

    // layer 1
    edge_kernel<40><<<egrid, blk, 0, stream>>>(x, 40, ei, ea, We1, be1, B1);
    node_kernel<40><<<ngrid, blk, 0, stream>>>(x, 40, B1, W1, b1, g1, bb1, m1, v1);
    // layer 2
    edge_kernel<64><<<egrid, blk, 0, stream>>>(B1, 64, ei, ea, We2, be2, B2);
    node_kernel<64><<<ngrid, blk, 0, stream>>>(B1, 64, B2, W2, b2, g2, bb2, m2, v2);
    // layer 3
    edge_kernel<64><<<egrid, blk, 0, stream>>>(B2, 64, ei, ea, We3, be3, B3);
    node_kernel<64><<<ngrid, blk, 0, stream>>>(B2, 64, B3, W3, b3, g3, bb3, m3, v3);
    // pool
    pool_kernel<<<pgrid, blk, 0, stream>>>(B3, batch, hpool);
    // head (MFMA)
    head_kernel<<<hgrid, blk, 0, stream>>>(B1, B2, B3, hpool, batch,
                                           Wl1, bl1, Wl2, bl2, out);
}

// Round 3
// 913.632 us; speedup vs baseline: 2.7500x; 1.7913x over previous
//
#include <hip/hip_runtime.h>
#include <hip/hip_bf16.h>

#define N_NODES 200000
#define N_EDGES 800000
#define N_MOL   10000
#define HDIM    64
#define EDGE_DIM 16
#define BN_EPS 1e-5f

typedef __attribute__((ext_vector_type(8))) short short8;
typedef __attribute__((ext_vector_type(4))) float f32x4;

// ---------------------------------------------------------------------------
// bf16 helpers
// ---------------------------------------------------------------------------
__device__ __forceinline__ unsigned int pk2(float a, float b) {
    __hip_bfloat162 h = __float22bfloat162_rn(make_float2(a, b));
    union { __hip_bfloat162 h; unsigned int u; } c;
    c.h = h;
    return c.u;
}
__device__ __forceinline__ short8 cvt8(float4 a, float4 b) {
    union { short8 s; unsigned int u[4]; } r;
    r.u[0] = pk2(a.x, a.y); r.u[1] = pk2(a.z, a.w);
    r.u[2] = pk2(b.x, b.y); r.u[3] = pk2(b.z, b.w);
    return r.s;
}
__device__ __forceinline__ float4 add4(float4 a, float4 b) {
    return make_float4(a.x + b.x, a.y + b.y, a.z + b.z, a.w + b.w);
}

// ---------------------------------------------------------------------------
// Edge kernel: msg = relu(x[src] + edge_attr @ We.T + be); atomicAdd into agg[dst]
// One 64-lane wave per edge (4 edges per 256-thread block).
// ---------------------------------------------------------------------------
template<int DIN>
__global__ __launch_bounds__(256) void edge_kernel(
    const float* __restrict__ xin, int stride_in,
    const int*   __restrict__ ei,     // [2, E]
    const float* __restrict__ ea,     // [E, 16]
    const float* __restrict__ We,     // [DIN, 16]
    const float* __restrict__ be,     // [DIN]
    float*       __restrict__ agg)    // [N, 64] (zeroed)
{
    int lane = threadIdx.x & 63;
    int e = blockIdx.x * 4 + (threadIdx.x >> 6);
    if (e >= N_EDGES) return;
    int src = ei[e];
    int dst = ei[N_EDGES + e];
    float eav = (lane < EDGE_DIM) ? ea[e * EDGE_DIM + lane] : 0.f;

    float ej[16];
#pragma unroll
    for (int j = 0; j < 16; j++) ej[j] = __shfl(eav, j, 64);

    int f = lane;
    if (f < DIN) {
        const float4* w4 = reinterpret_cast<const float4*>(We + f * 16);
        float acc = be[f];
#pragma unroll
        for (int j = 0; j < 4; j++) {
            float4 w = w4[j];
            acc += w.x * ej[4 * j + 0] + w.y * ej[4 * j + 1]
                 + w.z * ej[4 * j + 2] + w.w * ej[4 * j + 3];
        }
        float msg = xin[(size_t)src * stride_in + f] + acc;
        msg = fmaxf(msg, 0.f);
        atomicAdd(&agg[(size_t)dst * HDIM + f], msg);
    }
}

// ---------------------------------------------------------------------------
// Node MFMA kernel: h = leaky_relu(BN((x + agg) @ W.T + b))
// One wave per 64 nodes. 16x16x32 bf16 MFMA, K padded 40->64 for layer 1.
// A = W rows (feat, k), B = (x+agg) rows (node, k).
// D: col=node (lane&15), rows=feat ft*16+(lane>>4)*4+{0..3} -> float4 store.
// ---------------------------------------------------------------------------
template<int DIN>
__global__ __launch_bounds__(256) void node_mfma(
    const float* __restrict__ xin,    // [N, DIN]
    const float* __restrict__ agg,    // [N, 64] (cols 0..DIN-1 valid)
    float*       __restrict__ Bout,   // [N, 64]
    const float* __restrict__ W,      // [64, DIN]
    const float* __restrict__ bias,
    const float* __restrict__ gam,
    const float* __restrict__ bet,
    const float* __restrict__ mean,
    const float* __restrict__ var)
{
    int lane = threadIdx.x & 63;
    int wave = blockIdx.x * 4 + (threadIdx.x >> 6);
    if (wave >= N_NODES / 64) return;
    int n0 = wave * 64;
    int r = lane & 15;
    int g = lane >> 4;

    const short8 zero8 = (short8){0, 0, 0, 0, 0, 0, 0, 0};

    // ---- B fragments: S = x + agg, 4 node-subtiles x 2 k-steps ----
    short8 zf[4][2];
#pragma unroll
    for (int nt = 0; nt < 4; nt++) {
        int node = n0 + nt * 16 + r;
        const float* xr = xin + (size_t)node * DIN;
        const float* ar = agg + (size_t)node * HDIM;
        float4 x0 = *(const float4*)(xr + g * 8);
        float4 x1 = *(const float4*)(xr + g * 8 + 4);
        float4 a0 = *(const float4*)(ar + g * 8);
        float4 a1 = *(const float4*)(ar + g * 8 + 4);
        zf[nt][0] = cvt8(add4(x0, a0), add4(x1, a1));
        if (DIN == 64) {
            x0 = *(const float4*)(xr + 32 + g * 8);
            x1 = *(const float4*)(xr + 36 + g * 8);
            a0 = *(const float4*)(ar + 32 + g * 8);
            a1 = *(const float4*)(ar + 36 + g * 8);
            zf[nt][1] = cvt8(add4(x0, a0), add4(x1, a1));
        } else {
            if (g == 0) {
                x0 = *(const float4*)(xr + 32);
                x1 = *(const float4*)(xr + 36);
                a0 = *(const float4*)(ar + 32);
                a1 = *(const float4*)(ar + 36);
                zf[nt][1] = cvt8(add4(x0, a0), add4(x1, a1));
            } else {
                zf[nt][1] = zero8;
            }
        }
    }

    const float4* b4  = (const float4*)bias;
    const float4* g4  = (const float4*)gam;
    const float4* be4 = (const float4*)bet;
    const float4* m4  = (const float4*)mean;
    const float4* v4  = (const float4*)var;

#pragma unroll
    for (int ft = 0; ft < 4; ft++) {
        // A fragments for feats ft*16 + r
        const float* wr = W + (size_t)(ft * 16 + r) * DIN;
        short8 af[2];
        {
            float4 w0 = *(const float4*)(wr + g * 8);
            float4 w1 = *(const float4*)(wr + g * 8 + 4);
            af[0] = cvt8(w0, w1);
            if (DIN == 64) {
                w0 = *(const float4*)(wr + 32 + g * 8);
                w1 = *(const float4*)(wr + 36 + g * 8);
                af[1] = cvt8(w0, w1);
            } else if (g == 0) {
                w0 = *(const float4*)(wr + 32);
                w1 = *(const float4*)(wr + 36);
                af[1] = cvt8(w0, w1);
            } else {
                af[1] = zero8;
            }
        }

        f32x4 acc[4];
#pragma unroll
        for (int nt = 0; nt < 4; nt++) acc[nt] = (f32x4){0.f, 0.f, 0.f, 0.f};

#pragma unroll
        for (int ks = 0; ks < 2; ks++) {
#pragma unroll
            for (int nt = 0; nt < 4; nt++) {
                acc[nt] = __builtin_amdgcn_mfma_f32_16x16x32_bf16(
                    af[ks], zf[nt][ks], acc[nt], 0, 0, 0);
            }
        }

        // epilogue: feats ft*16 + g*4 + {0..3} (consecutive) for node n0+nt*16+r
        int idx = ft * 4 + g;
        float4 bb = b4[idx], gg = g4[idx], bt = be4[idx], mm = m4[idx], vv = v4[idx];
        float s0 = gg.x * rsqrtf(vv.x + BN_EPS);
        float s1 = gg.y * rsqrtf(vv.y + BN_EPS);
        float s2 = gg.z * rsqrtf(vv.z + BN_EPS);
        float s3 = gg.w * rsqrtf(vv.w + BN_EPS);
#pragma unroll
        for (int nt = 0; nt < 4; nt++) {
            int node = n0 + nt * 16 + r;
            float y0 = s0 * (acc[nt][0] + bb.x - mm.x) + bt.x;
            float y1 = s1 * (acc[nt][1] + bb.y - mm.y) + bt.y;
            float y2 = s2 * (acc[nt][2] + bb.z - mm.z) + bt.z;
            float y3 = s3 * (acc[nt][3] + bb.w - mm.w) + bt.w;
            y0 = (y0 > 0.f) ? y0 : 0.01f * y0;
            y1 = (y1 > 0.f) ? y1 : 0.01f * y1;
            y2 = (y2 > 0.f) ? y2 : 0.01f * y2;
            y3 = (y3 > 0.f) ? y3 : 0.01f * y3;
            *(float4*)(Bout + (size_t)node * HDIM + ft * 16 + g * 4) =
                make_float4(y0, y1, y2, y3);
        }
    }
}

// ---------------------------------------------------------------------------
// Pool kernel: hpool[batch[i]] += h3[i]
// ---------------------------------------------------------------------------
__global__ __launch_bounds__(256) void pool_kernel(
    const float* __restrict__ h3,
    const int*   __restrict__ batch,
    float*       __restrict__ hpool)
{
    int gid = blockIdx.x * 256 + threadIdx.x;
    if (gid >= N_NODES * HDIM) return;
    int i = gid >> 6, f = gid & 63;
    atomicAdd(&hpool[(size_t)batch[i] * HDIM + f], h3[gid]);
}

// ---------------------------------------------------------------------------
// Head: out[i] = Wl2 . leaky(Wl1 @ z_i + bl1) + bl2,  z_i = [h1|h2|h3|hpool[batch]]
// MFMA 16x16x32 bf16, fp32 accum. One wave per 64 nodes.
// ---------------------------------------------------------------------------
__global__ __launch_bounds__(256) void head_kernel(
    const float* __restrict__ h1, const float* __restrict__ h2,
    const float* __restrict__ h3, const float* __restrict__ hpool,
    const int*   __restrict__ batch,
    const float* __restrict__ Wl1, const float* __restrict__ bl1,
    const float* __restrict__ Wl2, const float* __restrict__ bl2,
    float*       __restrict__ out)
{
    int lane = threadIdx.x & 63;
    int wave = blockIdx.x * 4 + (threadIdx.x >> 6);
    if (wave >= N_NODES / 64) return;
    int n0 = wave * 64;
    int r = lane & 15;       // node within subtile (B col) / A row
    int g = lane >> 4;       // k-group

    short8 zf[4][8];
#pragma unroll
    for (int nt = 0; nt < 4; nt++) {
        int node = n0 + nt * 16 + r;
        const float* r1 = h1 + (size_t)node * 64;
        const float* r2 = h2 + (size_t)node * 64;
        const float* r3 = h3 + (size_t)node * 64;
        const float* rp = hpool + (size_t)batch[node] * 64;
        const float4* q;
        q = (const float4*)(r1 + g * 8);        zf[nt][0] = cvt8(q[0], q[1]);
        q = (const float4*)(r1 + 32 + g * 8);   zf[nt][1] = cvt8(q[0], q[1]);
        q = (const float4*)(r2 + g * 8);        zf[nt][2] = cvt8(q[0], q[1]);
        q = (const float4*)(r2 + 32 + g * 8);   zf[nt][3] = cvt8(q[0], q[1]);
        q = (const float4*)(r3 + g * 8);        zf[nt][4] = cvt8(q[0], q[1]);
        q = (const float4*)(r3 + 32 + g * 8);   zf[nt][5] = cvt8(q[0], q[1]);
        q = (const float4*)(rp + g * 8);        zf[nt][6] = cvt8(q[0], q[1]);
        q = (const float4*)(rp + 32 + g * 8);   zf[nt][7] = cvt8(q[0], q[1]);
    }

    float p[4] = {0.f, 0.f, 0.f, 0.f};

    const float4* bl1_4 = (const float4*)bl1;
    const float4* wl2_4 = (const float4*)Wl2;

#pragma unroll 1
    for (int ft = 0; ft < 16; ft++) {
        const float* arow = Wl1 + (size_t)(ft * 16 + r) * 256 + g * 8;
        short8 af[8];
#pragma unroll
        for (int ks = 0; ks < 8; ks++) {
            const float4* q = (const float4*)(arow + ks * 32);
            af[ks] = cvt8(q[0], q[1]);
        }

        f32x4 acc[4];
#pragma unroll
        for (int nt = 0; nt < 4; nt++) acc[nt] = (f32x4){0.f, 0.f, 0.f, 0.f};

#pragma unroll
        for (int ks = 0; ks < 8; ks++) {
#pragma unroll
            for (int nt = 0; nt < 4; nt++) {
                acc[nt] = __builtin_amdgcn_mfma_f32_16x16x32_bf16(
                    af[ks], zf[nt][ks], acc[nt], 0, 0, 0);
            }
        }

        float4 bl = bl1_4[ft * 4 + g];
        float4 w2 = wl2_4[ft * 4 + g];
#pragma unroll
        for (int nt = 0; nt < 4; nt++) {
            float a0 = acc[nt][0] + bl.x;
            float a1 = acc[nt][1] + bl.y;
            float a2 = acc[nt][2] + bl.z;
            float a3 = acc[nt][3] + bl.w;
            a0 = (a0 > 0.f) ? a0 : 0.01f * a0;
            a1 = (a1 > 0.f) ? a1 : 0.01f * a1;
            a2 = (a2 > 0.f) ? a2 : 0.01f * a2;
            a3 = (a3 > 0.f) ? a3 : 0.01f * a3;
            p[nt] += w2.x * a0 + w2.y * a1 + w2.z * a2 + w2.w * a3;
        }
    }

    float b2 = bl2[0];
#pragma unroll
    for (int nt = 0; nt < 4; nt++) {
        float s = p[nt];
        s += __shfl_xor(s, 16, 64);
        s += __shfl_xor(s, 32, 64);
        if (g == 0) out[n0 + nt * 16 + r] = s + b2;
    }
}

// ---------------------------------------------------------------------------
extern "C" void kernel_launch(void* const* d_in, const int* in_sizes, int n_in,
                              void* d_out, int out_size, void* d_ws, size_t ws_size,
                              hipStream_t stream) {
    const float* x     = (const float*)d_in[0];
    const int*   ei    = (const int*)  d_in[1];
    const float* ea    = (const float*)d_in[2];
    const int*   batch = (const int*)  d_in[3];

    const float* We1 = (const float*)d_in[4];  const float* be1 = (const float*)d_in[5];
    const float* W1  = (const float*)d_in[6];  const float* b1  = (const float*)d_in[7];
    const float* g1  = (const float*)d_in[8];  const float* bb1 = (const float*)d_in[9];
    const float* m1  = (const float*)d_in[10]; const float* v1  = (const float*)d_in[11];

    const float* We2 = (const float*)d_in[12]; const float* be2 = (const float*)d_in[13];
    const float* W2  = (const float*)d_in[14]; const float* b2  = (const float*)d_in[15];
    const float* g2  = (const float*)d_in[16]; const float* bb2 = (const float*)d_in[17];
    const float* m2  = (const float*)d_in[18]; const float* v2  = (const float*)d_in[19];

    const float* We3 = (const float*)d_in[20]; const float* be3 = (const float*)d_in[21];
    const float* W3  = (const float*)d_in[22]; const float* b3  = (const float*)d_in[23];
    const float* g3  = (const float*)d_in[24]; const float* bb3 = (const float*)d_in[25];
    const float* m3  = (const float*)d_in[26]; const float* v3  = (const float*)d_in[27];

    const float* Wl1 = (const float*)d_in[28]; const float* bl1 = (const float*)d_in[29];
    const float* Wl2 = (const float*)d_in[30]; const float* bl2 = (const float*)d_in[31];

    float* out = (float*)d_out;

    float* B1    = (float*)d_ws;                 // [N,64] agg1 -> h1
    float* B2    = B1 + (size_t)N_NODES * HDIM;  // [N,64] agg2 -> h2
    float* B3    = B2 + (size_t)N_NODES * HDIM;  // [N,64] agg3 -> h3
    float* hpool = B3 + (size_t)N_NODES * HDIM;  // [N_MOL,64]

    size_t zero_bytes = ((size_t)3 * N_NODES * HDIM + (size_t)N_MOL * HDIM) * sizeof(float);
    hipMemsetAsync(B1, 0, zero_bytes, stream);

    dim3 blk(256);
    dim3 egrid(N_EDGES / 4);
    dim3 ngrid((N_NODES / 64 + 3) / 4);
    dim3 pgrid((N_NODES * HDIM) / 256);
    dim3 hgrid((N_NODES / 64 + 3) / 4);

    // layer 1
    edge_kernel<40><<<egrid, blk, 0, stream>>>(x, 40, ei, ea, We1, be1, B1);
    node_mfma<40><<<ngrid, blk, 0, stream>>>(x, B1, B1, W1, b1, g1, bb1, m1, v1);
    // layer 2
    edge_kernel<64><<<egrid, blk, 0, stream>>>(B1, 64, ei, ea, We2, be2, B2);
    node_mfma<64><<<ngrid, blk, 0, stream>>>(B1, B2, B2, W2, b2, g2, bb2, m2, v2);
    // layer 3
    edge_kernel<64><<<egrid, blk, 0, stream>>>(B2, 64, ei, ea, We3, be3, B3);
    node_mfma<64><<<ngrid, blk, 0, stream>>>(B2, B3, B3, W3, b3, g3, bb3, m3, v3);
    // pool
    pool_kernel<<<pgrid, blk, 0, stream>>>(B3, batch, hpool);
    // head (MFMA)
    head_kernel<<<hgrid, blk, 0, stream>>>(B1, B2, B3, hpool, batch,
                                           Wl1, bl1, Wl2, bl2, out);
}

// Round 4
// 771.749 us; speedup vs baseline: 3.2556x; 1.1838x over previous
//
#include <hip/hip_runtime.h>
#include <hip/hip_bf16.h>

#define N_NODES 200000
#define N_EDGES 800000
#define N_MOL   10000
#define HDIM    64
#define EDGE_DIM 16
#define BN_EPS 1e-5f

typedef __attribute__((ext_vector_type(8))) short short8;
typedef __attribute__((ext_vector_type(4))) float f32x4;

// ---------------------------------------------------------------------------
// bf16 helpers
// ---------------------------------------------------------------------------
__device__ __forceinline__ unsigned int pk2(float a, float b) {
    __hip_bfloat162 h = __float22bfloat162_rn(make_float2(a, b));
    union { __hip_bfloat162 h; unsigned int u; } c;
    c.h = h;
    return c.u;
}
__device__ __forceinline__ short8 cvt8(float4 a, float4 b) {
    union { short8 s; unsigned int u[4]; } r;
    r.u[0] = pk2(a.x, a.y); r.u[1] = pk2(a.z, a.w);
    r.u[2] = pk2(b.x, b.y); r.u[3] = pk2(b.z, b.w);
    return r.s;
}
__device__ __forceinline__ float4 add4(float4 a, float4 b) {
    return make_float4(a.x + b.x, a.y + b.y, a.z + b.z, a.w + b.w);
}

// ---------------------------------------------------------------------------
// Edge kernel, 4 edges per wave: msg = relu(x[src] + ea @ We.T + be);
// atomicAdd into agg[dst]. Lane = feature; edge indices via scalar loads;
// ea via one coalesced 256B load; 4 independent x-row loads -> 4x MLP.
// ---------------------------------------------------------------------------
template<int DIN>
__global__ __launch_bounds__(256) void edge_kernel4(
    const float* __restrict__ xin, int stride_in,
    const int*   __restrict__ ei,     // [2, E]
    const float* __restrict__ ea,     // [E, 16]
    const float* __restrict__ We,     // [DIN, 16]
    const float* __restrict__ be,     // [DIN]
    float*       __restrict__ agg)    // [N, 64] (zeroed)
{
    int lane = threadIdx.x & 63;
    int w = blockIdx.x * 4 + (threadIdx.x >> 6);
    int e0 = w * 4;
    if (e0 >= N_EDGES) return;

    // wave-uniform edge indices -> scalar loads (contiguous dwordx4)
    int src[4], dst[4];
#pragma unroll
    for (int k = 0; k < 4; k++) {
        src[k] = ei[e0 + k];
        dst[k] = ei[N_EDGES + e0 + k];
    }

    // one coalesced load covers all 4 edges' attrs: lane -> edge(lane>>4), attr(lane&15)
    float eav = ea[(size_t)(e0 + (lane >> 4)) * EDGE_DIM + (lane & 15)];

    // 4 independent x-row loads (f = lane)
    int f = lane;
    float xv[4];
#pragma unroll
    for (int k = 0; k < 4; k++)
        xv[k] = (f < DIN) ? xin[(size_t)src[k] * stride_in + f] : 0.f;

    // We row + bias for this feature (loaded once)
    float4 wr0, wr1, wr2, wr3;
    float bias = 0.f;
    if (f < DIN) {
        const float4* w4 = reinterpret_cast<const float4*>(We + f * 16);
        wr0 = w4[0]; wr1 = w4[1]; wr2 = w4[2]; wr3 = w4[3];
        bias = be[f];
    }

#pragma unroll
    for (int k = 0; k < 4; k++) {
        float ej[16];
#pragma unroll
        for (int j = 0; j < 16; j++) ej[j] = __shfl(eav, k * 16 + j, 64);
        if (f < DIN) {
            float acc = bias;
            acc += wr0.x * ej[0]  + wr0.y * ej[1]  + wr0.z * ej[2]  + wr0.w * ej[3];
            acc += wr1.x * ej[4]  + wr1.y * ej[5]  + wr1.z * ej[6]  + wr1.w * ej[7];
            acc += wr2.x * ej[8]  + wr2.y * ej[9]  + wr2.z * ej[10] + wr2.w * ej[11];
            acc += wr3.x * ej[12] + wr3.y * ej[13] + wr3.z * ej[14] + wr3.w * ej[15];
            float msg = fmaxf(xv[k] + acc, 0.f);
            atomicAdd(&agg[(size_t)dst[k] * HDIM + f], msg);
        }
    }
}

// ---------------------------------------------------------------------------
// Node MFMA kernel: h = leaky_relu(BN((x + agg) @ W.T + b))
// ---------------------------------------------------------------------------
template<int DIN>
__global__ __launch_bounds__(256) void node_mfma(
    const float* __restrict__ xin,    // [N, DIN]
    const float* __restrict__ agg,    // [N, 64] (cols 0..DIN-1 valid)
    float*       __restrict__ Bout,   // [N, 64]
    const float* __restrict__ W,      // [64, DIN]
    const float* __restrict__ bias,
    const float* __restrict__ gam,
    const float* __restrict__ bet,
    const float* __restrict__ mean,
    const float* __restrict__ var)
{
    int lane = threadIdx.x & 63;
    int wave = blockIdx.x * 4 + (threadIdx.x >> 6);
    if (wave >= N_NODES / 64) return;
    int n0 = wave * 64;
    int r = lane & 15;
    int g = lane >> 4;

    const short8 zero8 = (short8){0, 0, 0, 0, 0, 0, 0, 0};

    short8 zf[4][2];
#pragma unroll
    for (int nt = 0; nt < 4; nt++) {
        int node = n0 + nt * 16 + r;
        const float* xr = xin + (size_t)node * DIN;
        const float* ar = agg + (size_t)node * HDIM;
        float4 x0 = *(const float4*)(xr + g * 8);
        float4 x1 = *(const float4*)(xr + g * 8 + 4);
        float4 a0 = *(const float4*)(ar + g * 8);
        float4 a1 = *(const float4*)(ar + g * 8 + 4);
        zf[nt][0] = cvt8(add4(x0, a0), add4(x1, a1));
        if (DIN == 64) {
            x0 = *(const float4*)(xr + 32 + g * 8);
            x1 = *(const float4*)(xr + 36 + g * 8);
            a0 = *(const float4*)(ar + 32 + g * 8);
            a1 = *(const float4*)(ar + 36 + g * 8);
            zf[nt][1] = cvt8(add4(x0, a0), add4(x1, a1));
        } else {
            if (g == 0) {
                x0 = *(const float4*)(xr + 32);
                x1 = *(const float4*)(xr + 36);
                a0 = *(const float4*)(ar + 32);
                a1 = *(const float4*)(ar + 36);
                zf[nt][1] = cvt8(add4(x0, a0), add4(x1, a1));
            } else {
                zf[nt][1] = zero8;
            }
        }
    }

    const float4* b4  = (const float4*)bias;
    const float4* g4  = (const float4*)gam;
    const float4* be4 = (const float4*)bet;
    const float4* m4  = (const float4*)mean;
    const float4* v4  = (const float4*)var;

#pragma unroll
    for (int ft = 0; ft < 4; ft++) {
        const float* wr = W + (size_t)(ft * 16 + r) * DIN;
        short8 af[2];
        {
            float4 w0 = *(const float4*)(wr + g * 8);
            float4 w1 = *(const float4*)(wr + g * 8 + 4);
            af[0] = cvt8(w0, w1);
            if (DIN == 64) {
                w0 = *(const float4*)(wr + 32 + g * 8);
                w1 = *(const float4*)(wr + 36 + g * 8);
                af[1] = cvt8(w0, w1);
            } else if (g == 0) {
                w0 = *(const float4*)(wr + 32);
                w1 = *(const float4*)(wr + 36);
                af[1] = cvt8(w0, w1);
            } else {
                af[1] = zero8;
            }
        }

        f32x4 acc[4];
#pragma unroll
        for (int nt = 0; nt < 4; nt++) acc[nt] = (f32x4){0.f, 0.f, 0.f, 0.f};

#pragma unroll
        for (int ks = 0; ks < 2; ks++) {
#pragma unroll
            for (int nt = 0; nt < 4; nt++) {
                acc[nt] = __builtin_amdgcn_mfma_f32_16x16x32_bf16(
                    af[ks], zf[nt][ks], acc[nt], 0, 0, 0);
            }
        }

        int idx = ft * 4 + g;
        float4 bb = b4[idx], gg = g4[idx], bt = be4[idx], mm = m4[idx], vv = v4[idx];
        float s0 = gg.x * rsqrtf(vv.x + BN_EPS);
        float s1 = gg.y * rsqrtf(vv.y + BN_EPS);
        float s2 = gg.z * rsqrtf(vv.z + BN_EPS);
        float s3 = gg.w * rsqrtf(vv.w + BN_EPS);
#pragma unroll
        for (int nt = 0; nt < 4; nt++) {
            int node = n0 + nt * 16 + r;
            float y0 = s0 * (acc[nt][0] + bb.x - mm.x) + bt.x;
            float y1 = s1 * (acc[nt][1] + bb.y - mm.y) + bt.y;
            float y2 = s2 * (acc[nt][2] + bb.z - mm.z) + bt.z;
            float y3 = s3 * (acc[nt][3] + bb.w - mm.w) + bt.w;
            y0 = (y0 > 0.f) ? y0 : 0.01f * y0;
            y1 = (y1 > 0.f) ? y1 : 0.01f * y1;
            y2 = (y2 > 0.f) ? y2 : 0.01f * y2;
            y3 = (y3 > 0.f) ? y3 : 0.01f * y3;
            *(float4*)(Bout + (size_t)node * HDIM + ft * 16 + g * 4) =
                make_float4(y0, y1, y2, y3);
        }
    }
}

// ---------------------------------------------------------------------------
// Pool kernel: hpool[batch[i]] += h3[i]
// ---------------------------------------------------------------------------
__global__ __launch_bounds__(256) void pool_kernel(
    const float* __restrict__ h3,
    const int*   __restrict__ batch,
    float*       __restrict__ hpool)
{
    int gid = blockIdx.x * 256 + threadIdx.x;
    if (gid >= N_NODES * HDIM) return;
    int i = gid >> 6, f = gid & 63;
    atomicAdd(&hpool[(size_t)batch[i] * HDIM + f], h3[gid]);
}

// ---------------------------------------------------------------------------
// Head: out[i] = Wl2 . leaky(Wl1 @ z_i + bl1) + bl2,  z_i = [h1|h2|h3|hpool[batch]]
// ---------------------------------------------------------------------------
__global__ __launch_bounds__(256) void head_kernel(
    const float* __restrict__ h1, const float* __restrict__ h2,
    const float* __restrict__ h3, const float* __restrict__ hpool,
    const int*   __restrict__ batch,
    const float* __restrict__ Wl1, const float* __restrict__ bl1,
    const float* __restrict__ Wl2, const float* __restrict__ bl2,
    float*       __restrict__ out)
{
    int lane = threadIdx.x & 63;
    int wave = blockIdx.x * 4 + (threadIdx.x >> 6);
    if (wave >= N_NODES / 64) return;
    int n0 = wave * 64;
    int r = lane & 15;
    int g = lane >> 4;

    short8 zf[4][8];
#pragma unroll
    for (int nt = 0; nt < 4; nt++) {
        int node = n0 + nt * 16 + r;
        const float* r1 = h1 + (size_t)node * 64;
        const float* r2 = h2 + (size_t)node * 64;
        const float* r3 = h3 + (size_t)node * 64;
        const float* rp = hpool + (size_t)batch[node] * 64;
        const float4* q;
        q = (const float4*)(r1 + g * 8);        zf[nt][0] = cvt8(q[0], q[1]);
        q = (const float4*)(r1 + 32 + g * 8);   zf[nt][1] = cvt8(q[0], q[1]);
        q = (const float4*)(r2 + g * 8);        zf[nt][2] = cvt8(q[0], q[1]);
        q = (const float4*)(r2 + 32 + g * 8);   zf[nt][3] = cvt8(q[0], q[1]);
        q = (const float4*)(r3 + g * 8);        zf[nt][4] = cvt8(q[0], q[1]);
        q = (const float4*)(r3 + 32 + g * 8);   zf[nt][5] = cvt8(q[0], q[1]);
        q = (const float4*)(rp + g * 8);        zf[nt][6] = cvt8(q[0], q[1]);
        q = (const float4*)(rp + 32 + g * 8);   zf[nt][7] = cvt8(q[0], q[1]);
    }

    float p[4] = {0.f, 0.f, 0.f, 0.f};

    const float4* bl1_4 = (const float4*)bl1;
    const float4* wl2_4 = (const float4*)Wl2;

#pragma unroll 1
    for (int ft = 0; ft < 16; ft++) {
        const float* arow = Wl1 + (size_t)(ft * 16 + r) * 256 + g * 8;
        short8 af[8];
#pragma unroll
        for (int ks = 0; ks < 8; ks++) {
            const float4* q = (const float4*)(arow + ks * 32);
            af[ks] = cvt8(q[0], q[1]);
        }

        f32x4 acc[4];
#pragma unroll
        for (int nt = 0; nt < 4; nt++) acc[nt] = (f32x4){0.f, 0.f, 0.f, 0.f};

#pragma unroll
        for (int ks = 0; ks < 8; ks++) {
#pragma unroll
            for (int nt = 0; nt < 4; nt++) {
                acc[nt] = __builtin_amdgcn_mfma_f32_16x16x32_bf16(
                    af[ks], zf[nt][ks], acc[nt], 0, 0, 0);
            }
        }

        float4 bl = bl1_4[ft * 4 + g];
        float4 w2 = wl2_4[ft * 4 + g];
#pragma unroll
        for (int nt = 0; nt < 4; nt++) {
            float a0 = acc[nt][0] + bl.x;
            float a1 = acc[nt][1] + bl.y;
            float a2 = acc[nt][2] + bl.z;
            float a3 = acc[nt][3] + bl.w;
            a0 = (a0 > 0.f) ? a0 : 0.01f * a0;
            a1 = (a1 > 0.f) ? a1 : 0.01f * a1;
            a2 = (a2 > 0.f) ? a2 : 0.01f * a2;
            a3 = (a3 > 0.f) ? a3 : 0.01f * a3;
            p[nt] += w2.x * a0 + w2.y * a1 + w2.z * a2 + w2.w * a3;
        }
    }

    float b2 = bl2[0];
#pragma unroll
    for (int nt = 0; nt < 4; nt++) {
        float s = p[nt];
        s += __shfl_xor(s, 16, 64);
        s += __shfl_xor(s, 32, 64);
        if (g == 0) out[n0 + nt * 16 + r] = s + b2;
    }
}

// ---------------------------------------------------------------------------
extern "C" void kernel_launch(void* const* d_in, const int* in_sizes, int n_in,
                              void* d_out, int out_size, void* d_ws, size_t ws_size,
                              hipStream_t stream) {
    const float* x     = (const float*)d_in[0];
    const int*   ei    = (const int*)  d_in[1];
    const float* ea    = (const float*)d_in[2];
    const int*   batch = (const int*)  d_in[3];

    const float* We1 = (const float*)d_in[4];  const float* be1 = (const float*)d_in[5];
    const float* W1  = (const float*)d_in[6];  const float* b1  = (const float*)d_in[7];
    const float* g1  = (const float*)d_in[8];  const float* bb1 = (const float*)d_in[9];
    const float* m1  = (const float*)d_in[10]; const float* v1  = (const float*)d_in[11];

    const float* We2 = (const float*)d_in[12]; const float* be2 = (const float*)d_in[13];
    const float* W2  = (const float*)d_in[14]; const float* b2  = (const float*)d_in[15];
    const float* g2  = (const float*)d_in[16]; const float* bb2 = (const float*)d_in[17];
    const float* m2  = (const float*)d_in[18]; const float* v2  = (const float*)d_in[19];

    const float* We3 = (const float*)d_in[20]; const float* be3 = (const float*)d_in[21];
    const float* W3  = (const float*)d_in[22]; const float* b3  = (const float*)d_in[23];
    const float* g3  = (const float*)d_in[24]; const float* bb3 = (const float*)d_in[25];
    const float* m3  = (const float*)d_in[26]; const float* v3  = (const float*)d_in[27];

    const float* Wl1 = (const float*)d_in[28]; const float* bl1 = (const float*)d_in[29];
    const float* Wl2 = (const float*)d_in[30]; const float* bl2 = (const float*)d_in[31];

    float* out = (float*)d_out;

    float* B1    = (float*)d_ws;                 // [N,64] agg1 -> h1
    float* B2    = B1 + (size_t)N_NODES * HDIM;  // [N,64] agg2 -> h2
    float* B3    = B2 + (size_t)N_NODES * HDIM;  // [N,64] agg3 -> h3
    float* hpool = B3 + (size_t)N_NODES * HDIM;  // [N_MOL,64]

    size_t zero_bytes = ((size_t)3 * N_NODES * HDIM + (size_t)N_MOL * HDIM) * sizeof(float);
    hipMemsetAsync(B1, 0, zero_bytes, stream);

    dim3 blk(256);
    dim3 egrid(N_EDGES / 16);                 // 4 waves/block, 4 edges/wave
    dim3 ngrid((N_NODES / 64 + 3) / 4);
    dim3 pgrid((N_NODES * HDIM) / 256);
    dim3 hgrid((N_NODES / 64 + 3) / 4);

    // layer 1
    edge_kernel4<40><<<egrid, blk, 0, stream>>>(x, 40, ei, ea, We1, be1, B1);
    node_mfma<40><<<ngrid, blk, 0, stream>>>(x, B1, B1, W1, b1, g1, bb1, m1, v1);
    // layer 2
    edge_kernel4<64><<<egrid, blk, 0, stream>>>(B1, 64, ei, ea, We2, be2, B2);
    node_mfma<64><<<ngrid, blk, 0, stream>>>(B1, B2, B2, W2, b2, g2, bb2, m2, v2);
    // layer 3
    edge_kernel4<64><<<egrid, blk, 0, stream>>>(B2, 64, ei, ea, We3, be3, B3);
    node_mfma<64><<<ngrid, blk, 0, stream>>>(B2, B3, B3, W3, b3, g3, bb3, m3, v3);
    // pool
    pool_kernel<<<pgrid, blk, 0, stream>>>(B3, batch, hpool);
    // head (MFMA)
    head_kernel<<<hgrid, blk, 0, stream>>>(B1, B2, B3, hpool, batch,
                                           Wl1, bl1, Wl2, bl2, out);
}